// Round 9
// baseline (684.770 us; speedup 1.0000x reference)
//
#include <hip/hip_runtime.h>

#define NG 1024
#define NT 200
#define NS 16
#define NM 4
#define NWAVES 8   // 8 groups per 512-thread block -> 2+ waves/SIMD co-resident

typedef float v2f __attribute__((ext_vector_type(2)));

// Compiler-only fence: stops IR reordering of barrier-free same-wave LDS
// write->read phases (HW DS pipe is in-order per wave).
#define LDS_FENCE() asm volatile("" ::: "memory")

// ---------- DPP fp64 row16 (16-lane) all-reduce ----------
template<int CTRL>
__device__ __forceinline__ double dpp_mov_d(double x) {
    const int lo = __double2loint(x), hi = __double2hiint(x);
    const int plo = __builtin_amdgcn_update_dpp(lo, lo, CTRL, 0xF, 0xF, false);
    const int phi = __builtin_amdgcn_update_dpp(hi, hi, CTRL, 0xF, 0xF, false);
    return __hiloint2double(phi, plo);
}
__device__ __forceinline__ double row16_allreduce_d(double x) {
    x += dpp_mov_d<0xB1>(x);   // xor1
    x += dpp_mov_d<0x4E>(x);   // xor2
    x += dpp_mov_d<0x141>(x);  // row_half_mirror == xor4 here
    x += dpp_mov_d<0x140>(x);  // row_mirror == xor8 here
    return x;
}

// ---------- ordered permlane pairs (select-free) ----------
// ISA-derived & r4-HW-consistent: with both operands = x, r[0] holds the
// even-16-row (resp. lower-32-half) value and r[1] the odd-row (upper-half)
// value, on EVERY lane.
__device__ __forceinline__ void pair16_d(double x, double& e, double& o) {
#if __has_builtin(__builtin_amdgcn_permlane16_swap)
    const unsigned lo = (unsigned)__double2loint(x), hi = (unsigned)__double2hiint(x);
    auto rl = __builtin_amdgcn_permlane16_swap(lo, lo, false, false);
    auto rh = __builtin_amdgcn_permlane16_swap(hi, hi, false, false);
    e = __hiloint2double((int)rh[0], (int)rl[0]);
    o = __hiloint2double((int)rh[1], (int)rl[1]);
#else
    const double p = __shfl_xor(x, 16, 64);
    const int odd = (threadIdx.x >> 4) & 1;
    e = odd ? p : x;  o = odd ? x : p;
#endif
}
__device__ __forceinline__ void pair32_d(double x, double& l, double& h) {
#if __has_builtin(__builtin_amdgcn_permlane32_swap)
    const unsigned lo = (unsigned)__double2loint(x), hi = (unsigned)__double2hiint(x);
    auto rl = __builtin_amdgcn_permlane32_swap(lo, lo, false, false);
    auto rh = __builtin_amdgcn_permlane32_swap(hi, hi, false, false);
    l = __hiloint2double((int)rh[0], (int)rl[0]);
    h = __hiloint2double((int)rh[1], (int)rl[1]);
#else
    const double p = __shfl_xor(x, 32, 64);
    const int up = (threadIdx.x >> 5) & 1;
    l = up ? p : x;  h = up ? x : p;
#endif
}
// sum over the 4 row-quads (lanes c, c+16, c+32, c+48), replicated
__device__ __forceinline__ double quad_sum_d(double x) {
    double e, o, l, h;
    pair16_d(x, e, o);
    const double s = e + o;
    pair32_d(s, l, h);
    return l + h;
}
__device__ __forceinline__ void pair16_f(float x, float& e, float& o) {
#if __has_builtin(__builtin_amdgcn_permlane16_swap)
    auto r = __builtin_amdgcn_permlane16_swap(__float_as_uint(x), __float_as_uint(x),
                                              false, false);
    e = __uint_as_float(r[0]); o = __uint_as_float(r[1]);
#else
    const float p = __shfl_xor(x, 16, 64);
    const int odd = (threadIdx.x >> 4) & 1;
    e = odd ? p : x;  o = odd ? x : p;
#endif
}
__device__ __forceinline__ void pair32_f(float x, float& l, float& h) {
#if __has_builtin(__builtin_amdgcn_permlane32_swap)
    auto r = __builtin_amdgcn_permlane32_swap(__float_as_uint(x), __float_as_uint(x),
                                              false, false);
    l = __uint_as_float(r[0]); h = __uint_as_float(r[1]);
#else
    const float p = __shfl_xor(x, 32, 64);
    const int up = (threadIdx.x >> 5) & 1;
    l = up ? p : x;  h = up ? x : p;
#endif
}

// Newton rsqrt: f32 seed + 2 fp64 iterations -> ~2ulp fp64 (s>0 guaranteed,
// R diag >= 1e-2). Replaces sqrt+div sequences in Cholesky.
__device__ __forceinline__ double nrsqrt_d(double x) {
#if __has_builtin(__builtin_amdgcn_rsq_f32)
    double r = (double)__builtin_amdgcn_rsq_f32((float)x);
#else
    double r = (double)rsqrtf((float)x);
#endif
    r = r * (1.5 - 0.5 * x * r * r);
    r = r * (1.5 - 0.5 * x * r * r);
    return r;
}

__global__ __launch_bounds__(512, 2)
void kalman_kernel(const float* __restrict__ input,      // [G,T,M]
                   const float* __restrict__ Fm,         // [S,S]
                   const float* __restrict__ Qm,         // [S,S]
                   const float* __restrict__ Hm,         // [M,S]
                   const float* __restrict__ Rm,         // [M,M]
                   const float* __restrict__ init_mean,  // [G,S]
                   const float* __restrict__ init_cov,   // [G,S,S]
                   float* __restrict__ out)
{
    const int lane = threadIdx.x & 63;
    const int wid  = threadIdx.x >> 6;          // 0..7
    const int g    = blockIdx.x * NWAVES + wid;
    const int c    = lane & 15;   // column index
    const int q    = lane >> 4;   // row-quad: lane owns rows 4q..4q+3 of col c

    // per-wave LDS scratch (no cross-wave sharing, no barriers)
    __shared__ __align__(16) float  lds3[NWAVES][NS][20];   // W transpose tile
    __shared__ __align__(16) double lds_K[NWAVES][NS][6];   // K rows (pad 6:
                  // 48B rows: 16B-aligned double2 reads, 2-way banks == free)
    __shared__ __align__(16) double lds_mean[NWAVES][NS];   // mean broadcast

    // ---- constants ----
    // E2[tp][j] = packed E[4q+tp][4j..4j+3], E = F - I (absolute j order;
    // off-diag E==F exactly, diagonal Sterbenz-exact)
    v2f E2[4][4][2];
    #pragma unroll
    for (int tp = 0; tp < 4; ++tp)
        #pragma unroll
        for (int j = 0; j < 4; ++j) {
            float4 v = *(const float4*)(Fm + (4*q + tp)*NS + 4*j);
            if (j == q) {   // diagonal of I lives at j==q, element tp
                if (tp == 0) v.x -= 1.0f;
                if (tp == 1) v.y -= 1.0f;
                if (tp == 2) v.z -= 1.0f;
                if (tp == 3) v.w -= 1.0f;
            }
            E2[tp][j][0] = (v2f){v.x, v.y};
            E2[tp][j][1] = (v2f){v.z, v.w};
        }
    // Ecq_d[tt] = (double)E[c][4q+tt]  (for mean predict)
    double Ecq_d[4];
    {
        const float4 v = *(const float4*)(Fm + c*NS + 4*q);
        float fc[4] = {v.x, v.y, v.z, v.w};
        fc[0] -= (c == 4*q+0) ? 1.0f : 0.0f;
        fc[1] -= (c == 4*q+1) ? 1.0f : 0.0f;
        fc[2] -= (c == 4*q+2) ? 1.0f : 0.0f;
        fc[3] -= (c == 4*q+3) ? 1.0f : 0.0f;
        Ecq_d[0]=fc[0]; Ecq_d[1]=fc[1]; Ecq_d[2]=fc[2]; Ecq_d[3]=fc[3];
    }
    double Hq_d[4][4]; // H[m][4q+t] (for pht)
    #pragma unroll
    for (int m = 0; m < 4; ++m) {
        const float4 v = *(const float4*)(Hm + m*NS + 4*q);
        Hq_d[m][0]=v.x; Hq_d[m][1]=v.y; Hq_d[m][2]=v.z; Hq_d[m][3]=v.w;
    }
    double Hc_d[4];    // H[m][c] (for S)
    #pragma unroll
    for (int m = 0; m < 4; ++m) Hc_d[m] = (double)Hm[m*NS + c];
    const double Hqc_d = (double)Hm[q*NS + c];   // H[q][c] (for hm)
    double Q_d[4];     // Q[4q+t][c]
    #pragma unroll
    for (int tt = 0; tt < 4; ++tt) Q_d[tt] = (double)Qm[(4*q + tt)*NS + c];
    // R lower triangle in fp64 (uniform -> SGPRs)
    const double R00=Rm[0],  R10=Rm[4],  R11=Rm[5],  R20=Rm[8],  R21=Rm[9];
    const double R22=Rm[10], R30=Rm[12], R31=Rm[13], R32=Rm[14], R33=Rm[15];

    // ---- state (fp64) ----
    double p_d[4];
    #pragma unroll
    for (int tt = 0; tt < 4; ++tt)
        p_d[tt] = (double)init_cov[g*NS*NS + (4*q + tt)*NS + c];
    double mean_c_d = (double)init_mean[g*NS + c];
    double mean_q_d[4];
    #pragma unroll
    for (int tt = 0; tt < 4; ++tt)
        mean_q_d[tt] = (double)init_mean[g*NS + 4*q + tt];

    // ---- output pointers ----
    float* pMean = out + (size_t)g*NT*NS + c;
    // P store: row c, cols 4q..4q+3 (valid: computed P symmetric to ~1e-16
    // rel; fp32 output rounding swamps it) -> one dwordx4, 1KB/wave/step
    float* pCov  = out + (size_t)NG*NT*NS + (size_t)g*NT*NS*NS + c*NS + 4*q;
    float* pMM   = out + (size_t)NG*NT*NS + (size_t)NG*NT*NS*NS + (size_t)g*NT*NM;
    float* pMC   = out + (size_t)NG*NT*NS + (size_t)NG*NT*NS*NS + (size_t)NG*NT*NM
                       + (size_t)g*NT*NM*NM;
    const float* pObsBase = input + (size_t)g*NT*NM;

    // depth-2 obs prefetch (16B/step cold HBM reads, ~900cyc latency)
    float4 obs   = *(const float4*)(pObsBase);
    float4 obs_n = *(const float4*)(pObsBase + NM);

    for (int t = 0; t < NT; ++t) {
        const int tpre = (t + 2 < NT) ? (t + 2) : (NT - 1);
        const float4 obs_nn = *(const float4*)(pObsBase + (size_t)tpre*NM);

        // ---- store state prediction for t ----
        if (q == 0) pMean[0] = (float)mean_c_d;
        *(float4*)pCov = make_float4((float)p_d[0], (float)p_d[1],
                                     (float)p_d[2], (float)p_d[3]);

        // ---- hm[q'] = (H mean)[q'] via c-dim row16 reduce + ordered gather ----
        double hm[4];
        {
            const double hq = row16_allreduce_d(Hqc_d * mean_c_d); // = hm[q]
            double e, o;
            pair16_d(hq, e, o);            // e = hm[even q of pair], o = odd
            pair32_d(e, hm[0], hm[2]);
            pair32_d(o, hm[1], hm[3]);
        }
        // ---- pht[n] = (H P)[n][c]  (fp64 quad sum, select-free) ----
        double pht[4];
        #pragma unroll
        for (int n = 0; n < 4; ++n) {
            pht[n] = quad_sum_d(p_d[0]*Hq_d[n][0] + p_d[1]*Hq_d[n][1]
                              + p_d[2]*Hq_d[n][2] + p_d[3]*Hq_d[n][3]);
        }

        // ---- S = H P H^T + R : lower triangle, fp64 row16 reduce ----
        const double s00 = row16_allreduce_d(Hc_d[0]*pht[0]) + R00;
        const double s10 = row16_allreduce_d(Hc_d[1]*pht[0]) + R10;
        const double s11 = row16_allreduce_d(Hc_d[1]*pht[1]) + R11;
        const double s20 = row16_allreduce_d(Hc_d[2]*pht[0]) + R20;
        const double s21 = row16_allreduce_d(Hc_d[2]*pht[1]) + R21;
        const double s22 = row16_allreduce_d(Hc_d[2]*pht[2]) + R22;
        const double s30 = row16_allreduce_d(Hc_d[3]*pht[0]) + R30;
        const double s31 = row16_allreduce_d(Hc_d[3]*pht[1]) + R31;
        const double s32 = row16_allreduce_d(Hc_d[3]*pht[2]) + R32;
        const double s33 = row16_allreduce_d(Hc_d[3]*pht[3]) + R33;

        // ---- measurement outputs for t ----
        if (lane == 0) {
            *(float4*)(pMM)      = make_float4((float)hm[0], (float)hm[1],
                                               (float)hm[2], (float)hm[3]);
            *(float4*)(pMC)      = make_float4((float)s00, (float)s10, (float)s20, (float)s30);
            *(float4*)(pMC + 4)  = make_float4((float)s10, (float)s11, (float)s21, (float)s31);
            *(float4*)(pMC + 8)  = make_float4((float)s20, (float)s21, (float)s22, (float)s32);
            *(float4*)(pMC + 12) = make_float4((float)s30, (float)s31, (float)s32, (float)s33);
        }
        pMean += NS; pCov += NS*NS; pMM += NM; pMC += NM*NM;
        if (t == NT-1) break;

        // ---- Cholesky (fp64; i_k = 1/l_kk via Newton rsqrt) ----
        const double i0  = nrsqrt_d(s00);
        const double L10 = s10*i0, L20 = s20*i0, L30 = s30*i0;
        const double i1  = nrsqrt_d(s11 - L10*L10);
        const double L21 = (s21 - L20*L10)*i1;
        const double L31 = (s31 - L30*L10)*i1;
        const double i2  = nrsqrt_d(s22 - L20*L20 - L21*L21);
        const double L32 = (s32 - L30*L20 - L31*L21)*i2;
        const double i3  = nrsqrt_d(s33 - L30*L30 - L31*L31 - L32*L32);

        // ---- K row c: solve S k = pht (fp64) ----
        const double y0 = pht[0]*i0;
        const double y1 = (pht[1] - L10*y0)*i1;
        const double y2 = (pht[2] - L20*y0 - L21*y1)*i2;
        const double y3 = (pht[3] - L30*y0 - L31*y1 - L32*y2)*i3;
        double Kc[4];
        Kc[3] = y3*i3;
        Kc[2] = (y2 - L32*Kc[3])*i2;
        Kc[1] = (y1 - L21*Kc[2] - L31*Kc[3])*i1;
        Kc[0] = (y0 - L10*Kc[1] - L20*Kc[2] - L30*Kc[3])*i0;

        const double r0 = (double)obs.x - hm[0], r1 = (double)obs.y - hm[1],
                     r2 = (double)obs.z - hm[2], r3 = (double)obs.w - hm[3];

        // mean_u[c] via the lane's own K row (c view)
        const double mu_c_d = mean_c_d + Kc[0]*r0 + Kc[1]*r1 + Kc[2]*r2 + Kc[3]*r3;

        // ---- K rows 4q+tt via LDS broadcast (fp64) ----
        if (q == 0) {
            *(double2*)&lds_K[wid][c][0] = make_double2(Kc[0], Kc[1]);
            *(double2*)&lds_K[wid][c][2] = make_double2(Kc[2], Kc[3]);
        }
        LDS_FENCE();
        double Kq[4][4];
        #pragma unroll
        for (int tt = 0; tt < 4; ++tt) {
            const double2 k0 = *(const double2*)&lds_K[wid][4*q + tt][0];
            const double2 k1 = *(const double2*)&lds_K[wid][4*q + tt][2];
            Kq[tt][0]=k0.x; Kq[tt][1]=k0.y; Kq[tt][2]=k1.x; Kq[tt][3]=k1.y;
        }

        // ---- cov_u (fp64) and mean_u (q view, fp64) ----
        double cu_d[4], mu_q_d[4];
        #pragma unroll
        for (int tt = 0; tt < 4; ++tt) {
            cu_d[tt] = p_d[tt] - (Kq[tt][0]*pht[0] + Kq[tt][1]*pht[1]
                                + Kq[tt][2]*pht[2] + Kq[tt][3]*pht[3]);
            mu_q_d[tt] = mean_q_d[tt] + Kq[tt][0]*r0 + Kq[tt][1]*r1
                                      + Kq[tt][2]*r2 + Kq[tt][3]*r3;
        }

        // ---- mean predict: mean_p = mean_u + E*mean_u (fp64) ----
        mean_c_d = mu_c_d + quad_sum_d(Ecq_d[0]*mu_q_d[0] + Ecq_d[1]*mu_q_d[1]
                                     + Ecq_d[2]*mu_q_d[2] + Ecq_d[3]*mu_q_d[3]);
        if (q == 0) lds_mean[wid][c] = mean_c_d;

        // ---- cov predict: P+ = cu + W + W^T + E cu E^T + Q (corrections fp32)
        // cu column allgather via ordered permlane (cu symmetric; no LDS):
        float cu_f[4];
        #pragma unroll
        for (int tt = 0; tt < 4; ++tt) cu_f[tt] = (float)cu_d[tt];
        v2f c2[4][2];   // c2[j] = packed cu[4j..4j+3][c]
        #pragma unroll
        for (int tt = 0; tt < 4; ++tt) {
            float e, o, v0, v1, v2, v3;
            pair16_f(cu_f[tt], e, o);
            pair32_f(e, v0, v2);   // cu[0+tt], cu[8+tt]
            pair32_f(o, v1, v3);   // cu[4+tt], cu[12+tt]
            c2[0][tt>>1][tt&1] = v0;
            c2[1][tt>>1][tt&1] = v1;
            c2[2][tt>>1][tt&1] = v2;
            c2[3][tt>>1][tt&1] = v3;
        }
        // W column: w[tp] = W[4q+tp][c] = sum_k E[4q+tp][k]*cu[k][c]
        float w[4];
        #pragma unroll
        for (int tp = 0; tp < 4; ++tp) {
            v2f acc = (v2f){0.0f, 0.0f};
            #pragma unroll
            for (int j = 0; j < 4; ++j) {
                acc += E2[tp][j][0] * c2[j][0];
                acc += E2[tp][j][1] * c2[j][1];
            }
            w[tp] = acc.x + acc.y;
        }
        // transpose W via LDS: write [row][col], read row c
        #pragma unroll
        for (int tp = 0; tp < 4; ++tp) lds3[wid][4*q + tp][c] = w[tp];
        LDS_FENCE();
        v2f rv2[4][2];          // row c of W, absolute chunks
        #pragma unroll
        for (int j = 0; j < 4; ++j) {
            const float4 v = *(const float4*)&lds3[wid][c][4*j];
            rv2[j][0] = (v2f){v.x, v.y};
            rv2[j][1] = (v2f){v.z, v.w};
        }
        float wt[4];            // W^T term: W[c][4q+tp]
        {
            const float4 v = *(const float4*)&lds3[wid][c][4*q];
            wt[0]=v.x; wt[1]=v.y; wt[2]=v.z; wt[3]=v.w;
        }
        // mean_q for next step (same fence covers lds_mean write->read)
        {
            const double2 m0 = *(const double2*)&lds_mean[wid][4*q];
            const double2 m1 = *(const double2*)&lds_mean[wid][4*q + 2];
            mean_q_d[0]=m0.x; mean_q_d[1]=m0.y; mean_q_d[2]=m1.x; mean_q_d[3]=m1.y;
        }
        // vv[tp] = (E cu E^T)[4q+tp][c] = sum_k E[4q+tp][k]*W[c][k]
        #pragma unroll
        for (int tp = 0; tp < 4; ++tp) {
            v2f acc = (v2f){0.0f, 0.0f};
            #pragma unroll
            for (int j = 0; j < 4; ++j) {
                acc += E2[tp][j][0] * rv2[j][0];
                acc += E2[tp][j][1] * rv2[j][1];
            }
            p_d[tp] = cu_d[tp] + Q_d[tp]
                    + (double)w[tp] + (double)wt[tp] + (double)(acc.x + acc.y);
        }

        // rotate obs pipeline
        obs = obs_n; obs_n = obs_nn;
    }
}

extern "C" void kernel_launch(void* const* d_in, const int* in_sizes, int n_in,
                              void* d_out, int out_size, void* d_ws, size_t ws_size,
                              hipStream_t stream)
{
    const float* input = (const float*)d_in[0];
    const float* F     = (const float*)d_in[1];
    const float* Q     = (const float*)d_in[2];
    const float* H     = (const float*)d_in[3];
    const float* R     = (const float*)d_in[4];
    const float* imean = (const float*)d_in[5];
    const float* icov  = (const float*)d_in[6];

    kalman_kernel<<<NG/NWAVES, 64*NWAVES, 0, stream>>>(input, F, Q, H, R,
                                                       imean, icov, (float*)d_out);
}